// Round 7
// baseline (165.323 us; speedup 1.0000x reference)
//
#include <hip/hip_runtime.h>

typedef __attribute__((ext_vector_type(8))) short bf16x8;
typedef __attribute__((ext_vector_type(4))) float f32x4;
typedef __attribute__((ext_vector_type(16))) float f32x16;

static __device__ __forceinline__ unsigned short f2bf(float f) {
    union { float f; unsigned int u; } v; v.f = f;
    unsigned int r = v.u + 0x7FFFu + ((v.u >> 16) & 1u);
    return (unsigned short)(r >> 16);
}

static __device__ __forceinline__ unsigned cvtpk_bf16(float lo, float hi) {
    unsigned r;
    asm("v_cvt_pk_bf16_f32 %0, %1, %2" : "=v"(r) : "v"(lo), "v"(hi));
    return r;
}

#define NRW (27 * 16384)

// Repack Wq/Wk/Wv -> RW[conv][kh][kw][cc][g][o][8s] bf16 (B-frag-ready), Wo -> bf16 [o][c]
__global__ __launch_bounds__(256) void repack_k(const float* __restrict__ Wq, const float* __restrict__ Wk,
                                                const float* __restrict__ Wv, const float* __restrict__ Wo,
                                                unsigned short* __restrict__ RW, unsigned short* __restrict__ WoB) {
    int t = blockIdx.x * 256 + threadIdx.x;
    if (t < NRW) {
        int s = t & 7, o = (t >> 3) & 127, g = (t >> 10) & 3, cc = (t >> 12) & 3, tap = t >> 14;
        int conv = tap / 9, kk = tap % 9, kh = kk / 3, kw = kk % 3;
        int c = cc * 32 + g * 8 + s;
        const float* W = (conv == 0) ? Wq : ((conv == 1) ? Wk : Wv);
        RW[t] = f2bf(W[((o * 128 + c) * 3 + kh) * 3 + kw]);
    } else {
        int u = t - NRW;
        if (u < 16384) WoB[u] = f2bf(Wo[u]);
    }
}

// Fused QKV 3x3 conv, implicit GEMM. Block = (b, h): M=64 (w), N=384 (3 convs x 128 o), K=1152.
__global__ __launch_bounds__(256) void qkv_conv_k(const float* __restrict__ x, const unsigned short* __restrict__ RW,
                                                  const float* __restrict__ bq, const float* __restrict__ bk,
                                                  const float* __restrict__ bv,
                                                  unsigned short* __restrict__ q_ws, unsigned short* __restrict__ k_ws,
                                                  unsigned short* __restrict__ v_ws) {
    __shared__ unsigned short xs[3 * 66 * 128];  // [kh][w+1 (66 padded)][c], swizzled ^((row&7)<<4)
    const int tid = threadIdx.x;
    const int b = blockIdx.x >> 6, h = blockIdx.x & 63;
    for (int i = tid; i < 3 * 66 * 128; i += 256) xs[i] = 0;
    __syncthreads();
    for (int ch = tid; ch < 3 * 128 * 16; ch += 256) {
        int r3 = ch >> 11, rem = ch & 2047, c = rem >> 4, w4 = rem & 15;
        int hh = h - 1 + r3;
        if (hh >= 0 && hh < 64) {
            float4 v = *(const float4*)(x + ((b * 128 + c) * 64 + hh) * 64 + w4 * 4);
            float vv[4] = {v.x, v.y, v.z, v.w};
#pragma unroll
            for (int j = 0; j < 4; ++j) {
                int wr = w4 * 4 + j + 1;
                unsigned int byte = (unsigned int)(((r3 * 66 + wr) * 128 + c) * 2) ^ ((wr & 7) << 4);
                *(unsigned short*)((char*)xs + byte) = f2bf(vv[j]);
            }
        }
    }
    __syncthreads();
    const int lane = tid & 63, wave = tid >> 6;
    const int l15 = lane & 15, g = lane >> 4;
    f32x4 acc[4][6];
#pragma unroll
    for (int i = 0; i < 4; ++i)
#pragma unroll
        for (int j = 0; j < 6; ++j) acc[i][j] = (f32x4){0.f, 0.f, 0.f, 0.f};
#pragma unroll 1
    for (int kk = 0; kk < 9; ++kk) {
        const int kw = kk % 3;
#pragma unroll 2
        for (int cc = 0; cc < 4; ++cc) {
            bf16x8 a[4];
#pragma unroll
            for (int mf = 0; mf < 4; ++mf) {
                int wr = mf * 16 + l15 + kw;
                unsigned int byte = (unsigned int)((((kk / 3) * 66 + wr) * 128 + cc * 32 + g * 8) * 2) ^ ((wr & 7) << 4);
                a[mf] = *(const bf16x8*)((const char*)xs + byte);
            }
#pragma unroll
            for (int n6 = 0; n6 < 6; ++n6) {
                int nt = wave * 6 + n6;
                int conv = nt >> 3;
                int o = (nt * 16 + l15) & 127;
                bf16x8 bfr = *(const bf16x8*)(RW + ((((conv * 9 + kk) * 4 + cc) * 4 + g) * 128 + o) * 8);
#pragma unroll
                for (int mf = 0; mf < 4; ++mf)
                    acc[mf][n6] = __builtin_amdgcn_mfma_f32_16x16x32_bf16(a[mf], bfr, acc[mf][n6], 0, 0, 0);
            }
        }
    }
    // 1/sqrt(128) * log2(e): q pre-scaled so attention softmax runs in exp2 domain
    const float SCALE2 = 0.08838834764831845f * 1.4426950408889634f;
#pragma unroll
    for (int n6 = 0; n6 < 6; ++n6) {
        int nt = wave * 6 + n6;
        int conv = nt >> 3;
        int o = (nt * 16 + l15) & 127;
        float bias = (conv == 0) ? bq[o] : ((conv == 1) ? bk[o] : bv[o]);
#pragma unroll
        for (int mf = 0; mf < 4; ++mf) {
#pragma unroll
            for (int r = 0; r < 4; ++r) {
                int pos = h * 64 + mf * 16 + g * 4 + r;
                float val = acc[mf][n6][r] + bias;
                if (conv == 0)      q_ws[(b * 4096 + pos) * 128 + o] = f2bf(val * SCALE2);
                else if (conv == 1) k_ws[(b * 4096 + pos) * 128 + o] = f2bf(val);
                else                v_ws[(b * 128 + o) * 4096 + pos] = f2bf(val);
            }
        }
    }
}

#define AS1C(p) ((const __attribute__((address_space(1))) void*)(p))
#define AS3(p)  ((__attribute__((address_space(3))) void*)(p))

// Flash attention + fused 1x1 conv + bias + residual.
// Block = (b, 64-row q tile), 4 waves = 2 wi (32 i) x 2 wj (32 j). KV tile = 64 j,
// double-buffered; 66KB LDS -> 2 blocks/CU. Softmax in exp2 domain (log2e folded into q).
// V pair-packed into 256B LDS super-rows (4-bit swizzle, conflict-free like K).
// Per-js fusion: exp->pack->PV per 16-j half so PV MFMAs overlap the other half's VALU.
__global__ __launch_bounds__(256, 2) void attn_k(
    const unsigned short* __restrict__ q_ws, const unsigned short* __restrict__ k_ws,
    const unsigned short* __restrict__ v_ws, const unsigned short* __restrict__ WoB,
    const float* __restrict__ bo, const float* __restrict__ x, float* __restrict__ out) {
    __shared__ __align__(16) char smem[66560];

    const int tid = threadIdx.x;
    const int lane = tid & 63, wave = tid >> 6;
    const int wj = wave & 1, wi = wave >> 1;
    const int l31 = lane & 31, h = lane >> 5;
    const int b = blockIdx.x & 7;              // batch -> XCD affinity (K/V in one XCD L2)
    const int qt = blockIdx.x >> 3;            // 0..63
    const int ibase = qt * 64;

    const char* kB = (const char*)(k_ws + (size_t)b * 4096 * 128);  // [j][c], 256B rows
    const char* vB = (const char*)(v_ws + (size_t)b * 128 * 4096);  // [c][j], 8192B rows

    // stage 64j tile kt into buffer buf: linear LDS dest, pre-swizzled global source.
    // K: 64 rows x 16 chunks, swz ^(row&15). V: pair-packed super-rows sr=crow>>1 (64 x 256B),
    // slot s8 = (crow&1)*8 + jchunk, swz ^(sr&15) -> conflict-free 16-chunk rows like K.
    auto stage = [&](int buf, int kt) {
        char* Kn = smem + buf * 32768;
        char* Vn = Kn + 16384;
#pragma unroll
        for (int q = 0; q < 4; ++q) {
            int slot = (wave * 4 + q) * 64 + lane;  // 0..1023
            int krow = slot >> 4, ks = slot & 15;
            int kcs = ks ^ (krow & 15);
            __builtin_amdgcn_global_load_lds(AS1C(kB + (size_t)(kt * 64 + krow) * 256 + kcs * 16),
                                             AS3(Kn + slot * 16), 16, 0, 0);
            int sr = slot >> 4, s8p = slot & 15;
            int s8 = s8p ^ (sr & 15);
            int crow = sr * 2 + (s8 >> 3), jch = s8 & 7;
            __builtin_amdgcn_global_load_lds(AS1C(vB + (size_t)crow * 8192 + kt * 128 + jch * 16),
                                             AS3(Vn + slot * 16), 16, 0, 0);
        }
    };

    stage(0, 0);  // prologue: tile 0 -> buffer 0

    // Q fragments: B-operand, col = i = wi*32 + l31, k=c
    bf16x8 qf[8];
    {
        const unsigned short* qrow = q_ws + ((size_t)b * 4096 + ibase + wi * 32 + l31) * 128;
#pragma unroll
        for (int cc = 0; cc < 8; ++cc) qf[cc] = *(const bf16x8*)(qrow + cc * 16 + h * 8);
    }

    f32x16 zero16;
#pragma unroll
    for (int r = 0; r < 16; ++r) zero16[r] = 0.f;
    f32x16 oac[4];
#pragma unroll
    for (int cf = 0; cf < 4; ++cf)
#pragma unroll
        for (int r = 0; r < 16; ++r) oac[cf][r] = 0.f;
    float m = -1e30f, ssum = 0.f;

    __syncthreads();  // tile 0 staged

#pragma unroll 1
    for (int kt = 0; kt < 64; ++kt) {
        const int cur = kt & 1;
        const char* Kc = smem + cur * 32768;
        const char* Vc = Kc + 16384;
        if (kt < 63) stage(cur ^ 1, kt + 1);  // prefetch (drained at end barrier)

        // S^T[j][i] = K·Q^T over this wave's 32-j slice (first MFMA consumes zero16 C)
        const int jrow = wj * 32 + l31;
        f32x16 st;
        __builtin_amdgcn_s_setprio(1);
        {
            unsigned byte = (unsigned)(jrow * 256 + ((h ^ (jrow & 15)) << 4));
            bf16x8 kf = *(const bf16x8*)(Kc + byte);
            st = __builtin_amdgcn_mfma_f32_32x32x16_bf16(kf, qf[0], zero16, 0, 0, 0);
        }
#pragma unroll
        for (int cc = 1; cc < 8; ++cc) {
            unsigned byte = (unsigned)(jrow * 256 + (((cc * 2 + h) ^ (jrow & 15)) << 4));
            bf16x8 kf = *(const bf16x8*)(Kc + byte);
            st = __builtin_amdgcn_mfma_f32_32x32x16_bf16(kf, qf[cc], st, 0, 0, 0);
        }
        __builtin_amdgcn_s_setprio(0);

        // max over 32 j: max3 tree (9 fused ops) + 1 xor32 shuffle
        float x0 = fmaxf(fmaxf(st[0], st[1]), st[2]);
        float x1 = fmaxf(fmaxf(st[3], st[4]), st[5]);
        float x2 = fmaxf(fmaxf(st[6], st[7]), st[8]);
        float x3 = fmaxf(fmaxf(st[9], st[10]), st[11]);
        float x4 = fmaxf(fmaxf(st[12], st[13]), st[14]);
        float y0 = fmaxf(fmaxf(x0, x1), x2);
        float y1 = fmaxf(fmaxf(x3, x4), st[15]);
        float tmax = fmaxf(y0, y1);
        tmax = fmaxf(tmax, __shfl_xor(tmax, 32));
        if (!__all(tmax <= m + 8.f)) {  // defer-rescale, THR=8 (log2 units)
            float mnew = fmaxf(m, tmax);
            float corr = exp2f(m - mnew);
            ssum *= corr;
#pragma unroll
            for (int cf = 0; cf < 4; ++cf)
#pragma unroll
                for (int r = 0; r < 16; ++r) oac[cf][r] *= corr;
            m = mnew;
        }

        // per-js: exp2 -> cvt_pk -> permlane32_swap -> PV (MFMAs overlap next half's VALU)
        // st[gq*4+r] holds j = 8gq + 4h + r; pa needs j = 16js + 8h + (0..7).
        float ps = 0.f;
#pragma unroll
        for (int js = 0; js < 2; ++js) {
            float pA0 = exp2f(st[8 * js + 0] - m);
            float pA1 = exp2f(st[8 * js + 1] - m);
            float pA2 = exp2f(st[8 * js + 2] - m);
            float pA3 = exp2f(st[8 * js + 3] - m);
            float pB0 = exp2f(st[8 * js + 4] - m);
            float pB1 = exp2f(st[8 * js + 5] - m);
            float pB2 = exp2f(st[8 * js + 6] - m);
            float pB3 = exp2f(st[8 * js + 7] - m);
            ps += ((pA0 + pA1) + (pA2 + pA3)) + ((pB0 + pB1) + (pB2 + pB3));
            unsigned a0 = cvtpk_bf16(pA0, pA1), a1 = cvtpk_bf16(pA2, pA3);
            unsigned b0 = cvtpk_bf16(pB0, pB1), b1 = cvtpk_bf16(pB2, pB3);
            auto r0 = __builtin_amdgcn_permlane32_swap(a0, b0, false, false);
            auto r1 = __builtin_amdgcn_permlane32_swap(a1, b1, false, false);
            union { unsigned w[4]; bf16x8 v; } pu;
            pu.w[0] = r0[0];
            pu.w[1] = r1[0];
            pu.w[2] = r0[1];
            pu.w[3] = r1[1];
            const int jch = wj * 4 + js * 2 + h;  // j-chunk this lane's PV A-frag needs
            __builtin_amdgcn_s_setprio(1);
#pragma unroll
            for (int cf = 0; cf < 4; ++cf) {
                int crow = cf * 32 + l31;
                int sr = crow >> 1;
                int s8 = ((crow & 1) << 3) | jch;
                unsigned vbyte = (unsigned)(sr * 256 + ((s8 ^ (sr & 15)) << 4));
                bf16x8 va = *(const bf16x8*)(Vc + vbyte);
                oac[cf] = __builtin_amdgcn_mfma_f32_32x32x16_bf16(va, pu.v, oac[cf], 0, 0, 0);
            }
            __builtin_amdgcn_s_setprio(0);
        }
        ps += __shfl_xor(ps, 32);
        ssum += ps;
        __syncthreads();  // prefetch drained + all reads of cur done -> next iter may restage
    }

    // ---- epilogue: 2-way split-KV combine (exp2 domain), then 1x1 conv + bias + residual ----
    float* sRed = (float*)(smem + 65536);  // [2 wj][64 i][2] (m, ssum)
    const int it = wi * 32 + l31;
    if (h == 0) {
        sRed[(wj * 64 + it) * 2] = m;
        sRed[(wj * 64 + it) * 2 + 1] = ssum;
    }
    __syncthreads();
    float m1 = sRed[((wj ^ 1) * 64 + it) * 2];
    float s1 = sRed[((wj ^ 1) * 64 + it) * 2 + 1];
    float M = fmaxf(m, m1);
    float aS = exp2f(m - M);
    float inv = 1.0f / (aS * ssum + exp2f(m1 - M) * s1);

    char* sBig = smem + 32768;  // f32 [64 i][128 c] swz ^((i&7)<<4), 32KB over buf1
    if (wj == 1) {
#pragma unroll
        for (int cf = 0; cf < 4; ++cf)
#pragma unroll
            for (int g = 0; g < 4; ++g) {
                int c = cf * 32 + g * 8 + 4 * h;
                f32x4 v4;
#pragma unroll
                for (int k = 0; k < 4; ++k) v4[k] = aS * oac[cf][4 * g + k];
                unsigned byte = (unsigned)(it * 512 + c * 4) ^ ((it & 7) << 4);
                *(f32x4*)(sBig + byte) = v4;
            }
    }
    __syncthreads();
    unsigned short* sOut = (unsigned short*)smem;  // bf16 [64 i][128 c] swz ^((i&15)<<4), 16KB
    if (wj == 0) {
#pragma unroll
        for (int cf = 0; cf < 4; ++cf)
#pragma unroll
            for (int g = 0; g < 4; ++g) {
                int c = cf * 32 + g * 8 + 4 * h;
                unsigned rbyte = (unsigned)(it * 512 + c * 4) ^ ((it & 7) << 4);
                f32x4 rd = *(const f32x4*)((const char*)sBig + rbyte);
                float u0 = (aS * oac[cf][4 * g + 0] + rd[0]) * inv;
                float u1 = (aS * oac[cf][4 * g + 1] + rd[1]) * inv;
                float u2 = (aS * oac[cf][4 * g + 2] + rd[2]) * inv;
                float u3 = (aS * oac[cf][4 * g + 3] + rd[3]) * inv;
                uint2 pk;
                pk.x = cvtpk_bf16(u0, u1);
                pk.y = cvtpk_bf16(u2, u3);
                unsigned wbyte = (unsigned)(it * 256 + c * 2) ^ ((it & 15) << 4);
                *(uint2*)((char*)sOut + wbyte) = pk;
            }
    }
    __syncthreads();

    // 1x1 conv: D[o][i] = Wo x out2, 8 tiles of 32x32 (4 of x 2 ifl) over 4 waves (2 each)
#pragma unroll
    for (int t = 0; t < 2; ++t) {
        int tt = wave * 2 + t;
        int of = tt >> 1, ifl = tt & 1;
        int ir = ifl * 32 + l31;
        f32x16 acc;
#pragma unroll
        for (int r = 0; r < 16; ++r) acc[r] = 0.f;
#pragma unroll
        for (int cc = 0; cc < 8; ++cc) {
            unsigned bbyte = (unsigned)(ir * 256 + cc * 32 + h * 16) ^ ((ir & 15) << 4);
            bf16x8 bfr = *(const bf16x8*)((const char*)sOut + bbyte);
            bf16x8 wa = *(const bf16x8*)(WoB + (of * 32 + l31) * 128 + cc * 16 + h * 8);
            acc = __builtin_amdgcn_mfma_f32_32x32x16_bf16(wa, bfr, acc, 0, 0, 0);
        }
        int iglob = ibase + ir;
#pragma unroll
        for (int r = 0; r < 16; ++r) {
            int o = of * 32 + (r & 3) + 8 * (r >> 2) + 4 * h;
            size_t gidx = ((size_t)b * 128 + o) * 4096 + iglob;
            out[gidx] = acc[r] + bo[o] + x[gidx];
        }
    }
}

extern "C" void kernel_launch(void* const* d_in, const int* in_sizes, int n_in,
                              void* d_out, int out_size, void* d_ws, size_t ws_size,
                              hipStream_t stream) {
    const float* x  = (const float*)d_in[0];
    const float* Wq = (const float*)d_in[1];
    const float* bq = (const float*)d_in[2];
    const float* Wk = (const float*)d_in[3];
    const float* bk = (const float*)d_in[4];
    const float* Wv = (const float*)d_in[5];
    const float* bv = (const float*)d_in[6];
    const float* Wo = (const float*)d_in[7];
    const float* bo = (const float*)d_in[8];
    char* ws = (char*)d_ws;
    unsigned short* q_ws = (unsigned short*)(ws);              //  8 MB  [b][n][c] bf16 (pre-scaled, log2e folded)
    unsigned short* k_ws = (unsigned short*)(ws + 8388608);    //  8 MB  [b][n][c] bf16
    unsigned short* v_ws = (unsigned short*)(ws + 16777216);   //  8 MB  [b][c][n] bf16
    unsigned short* RW   = (unsigned short*)(ws + 25165824);   //  884 KB repacked qkv weights
    unsigned short* WoB  = (unsigned short*)(ws + 26050560);   //  32 KB  Wo bf16
    float* out = (float*)d_out;

    hipLaunchKernelGGL(repack_k, dim3(1792), dim3(256), 0, stream, Wq, Wk, Wv, Wo, RW, WoB);
    hipLaunchKernelGGL(qkv_conv_k, dim3(512), dim3(256), 0, stream, x, RW, bq, bk, bv, q_ws, k_ws, v_ws);
    hipLaunchKernelGGL(attn_k, dim3(512), dim3(256), 0, stream, q_ws, k_ws, v_ws, WoB, bo, x, out);
}